// Round 2
// baseline (311.983 us; speedup 1.0000x reference)
//
#include <hip/hip_runtime.h>
#include <hip/hip_cooperative_groups.h>
#include <stdint.h>

// Problem constants (from reference)
#define B_   8
#define N_   1024
#define C_   256      // C == C_OUT == 256
#define E_   16384
#define BN_  (B_ * N_)        // 8192
#define NW_  (N_ / 32)        // 32 mask words per row
#define LIST_CAP 96           // per-wave LDS neighbor list; Poisson(16) tail ~0

typedef __attribute__((ext_vector_type(8))) short bf16x8;
typedef __attribute__((ext_vector_type(4))) float f32x4;

static __device__ __forceinline__ short f32_to_bf16(float f) {
  uint32_t u = __float_as_uint(f);
  uint32_t r = (u + 0x7fffu + ((u >> 16) & 1u)) >> 16;   // RNE
  return (short)r;
}
static __device__ __forceinline__ float bf16_to_f32(short s) {
  return __uint_as_float(((uint32_t)(uint16_t)s) << 16);
}

// ---------------------------------------------------------------------------
// Fused cooperative kernel: {zero mask} -> grid.sync -> {scatter edges}
// -> grid.sync -> {Z = dinv * (X @ W^T)}.
// Replaces 3 serialized dispatches (hipMemset, scatter, gemm) with one —
// dispatch-boundary overhead, not kernel math, is the measured residual.
// 512 blocks x 256 threads: LDS 66.3 KB -> exactly 2 blocks/CU -> all 512
// co-resident (cooperative-launch requirement holds).
// __threadfence() on both sides of each grid.sync(): writer-side L2
// writeback AND reader-side invalidate across non-coherent per-XCD L2s (G16).
__global__ __launch_bounds__(256) void fused_pre(
    const float* __restrict__ X, const int* __restrict__ ei,
    const float* __restrict__ W, uint32_t* __restrict__ mask,
    float* __restrict__ Z) {
  // Chunk-major B-tile: Bh[chunk][row][8] shorts.
  //  - stage write: lanes 0..63 -> rows 0..63, same chunk -> 1024B contiguous
  //    ds_write_b128, conflict-free.
  //  - frag read: quarter-wave reads rows nt*16..+15, same chunk -> 256B
  //    contiguous ds_read_b128, conflict-free (2-way is free per m136).
  __shared__ __attribute__((aligned(16))) short Bh[32][64][8];  // 32 KB
  __shared__ __attribute__((aligned(16))) short Bl[32][64][8];  // 32 KB
  __shared__ int   dpart[4][64];
  __shared__ float dinv_s[64];

  cooperative_groups::grid_group gg = cooperative_groups::this_grid();

  int t    = threadIdx.x;
  int id   = blockIdx.x;           // 0..511
  int gtid = id * 256 + t;         // 0..131071

  // ---- phase 0: zero the 1 MB mask (131072 threads x 8 B) ----
  ((uint2*)mask)[gtid] = make_uint2(0u, 0u);
  __threadfence();
  gg.sync();
  __threadfence();

  // ---- phase 1: scatter edges, one per thread (E*B == 131072) ----
  {
    int b   = gtid & (B_ - 1);                     // layout [E, B]
    int src = ei[gtid];                            // edge_index[0] flat
    int dst = ei[E_ * B_ + gtid];                  // edge_index[1] flat
    atomicOr(&mask[(size_t)(b * N_ + src) * NW_ + (dst >> 5)], 1u << (dst & 31));
  }
  __threadfence();
  gg.sync();
  __threadfence();

  // ---- phase 2: Z = dinv[m] * (X @ W^T), bf16x3 split MFMA ----
  // Tile swizzle: XCD x (= id&7 under hw round-robin) owns m-tiles of
  // batch x -> X re-reads L2-local; Z slice (1 MB/XCD) is what aggregate's
  // batch=blk&7 swizzle reads back from the same XCD's L2.
  int loc = id >> 3;               // 0..63  (per-XCD local id)
  int mt  = (id & 7) * 16 + (loc >> 2);   // m-tile 0..127; XCD x -> batch x
  int m0  = mt * 64;
  int n0  = (loc & 3) * 64;        // all 4 n-tiles of an m-panel on same XCD

  // inline degree: popcount of mask rows m0..m0+63
  {
    int row = t & 63, part = t >> 6;               // 4 threads per row
    const uint4* mp =
        (const uint4*)&mask[(size_t)(m0 + row) * NW_ + part * 8];
    uint4 a = mp[0], b = mp[1];
    dpart[part][row] = __popc(a.x) + __popc(a.y) + __popc(a.z) + __popc(a.w) +
                       __popc(b.x) + __popc(b.y) + __popc(b.z) + __popc(b.w);
  }

  // stage whole W-tile (rows n0..n0+63, K=0..256) as hi/lo bf16
#pragma unroll
  for (int i = 0; i < 8; i++) {
    int row = t & 63;
    int ch  = (t >> 6) * 8 + i;
    const float* wr = &W[(size_t)(n0 + row) * C_ + ch * 8];
    float w8[8];
    *(float4*)&w8[0] = *(const float4*)&wr[0];
    *(float4*)&w8[4] = *(const float4*)&wr[4];
    bf16x8 wh, wl;
#pragma unroll
    for (int j = 0; j < 8; j++) {
      short h = f32_to_bf16(w8[j]);
      wh[j] = h;
      wl[j] = f32_to_bf16(w8[j] - bf16_to_f32(h));
    }
    *(bf16x8*)&Bh[ch][row][0] = wh;
    *(bf16x8*)&Bl[ch][row][0] = wl;
  }
  __syncthreads();                 // covers dpart + Bh/Bl

  if (t < 64) {                    // wave 0 computes dinv while others compute
    int d = dpart[0][t] + dpart[1][t] + dpart[2][t] + dpart[3][t] + 1;
    dinv_s[t] = rsqrtf((float)d);
  }

  int wv = t >> 6;                 // wave 0..3 -> rows 16wv..16wv+15
  int ln = t & 63;
  int lm = ln & 15;                // frag row-in-tile
  int qd = ln >> 4;                // frag k-quad

  const float* xr = &X[(size_t)(m0 + 16 * wv + lm) * C_ + qd * 8];

  f32x4 acc[4];
#pragma unroll
  for (int i = 0; i < 4; i++) acc[i] = (f32x4){0.f, 0.f, 0.f, 0.f};

  // barrier-free K loop: A from global, B from resident LDS
#pragma unroll
  for (int k0 = 0; k0 < C_; k0 += 32) {
    float xv[8];
    *(float4*)&xv[0] = *(const float4*)&xr[k0];
    *(float4*)&xv[4] = *(const float4*)&xr[k0 + 4];
    bf16x8 ah, al;
#pragma unroll
    for (int j = 0; j < 8; j++) {
      short h = f32_to_bf16(xv[j]);
      ah[j] = h;
      al[j] = f32_to_bf16(xv[j] - bf16_to_f32(h));
    }
    int cq = (k0 >> 3) + qd;
#pragma unroll
    for (int nt = 0; nt < 4; nt++) {
      bf16x8 bh = *(const bf16x8*)&Bh[cq][nt * 16 + lm][0];
      bf16x8 bl = *(const bf16x8*)&Bl[cq][nt * 16 + lm][0];
      acc[nt] = __builtin_amdgcn_mfma_f32_16x16x32_bf16(ah, bh, acc[nt], 0, 0, 0);
      acc[nt] = __builtin_amdgcn_mfma_f32_16x16x32_bf16(ah, bl, acc[nt], 0, 0, 0);
      acc[nt] = __builtin_amdgcn_mfma_f32_16x16x32_bf16(al, bh, acc[nt], 0, 0, 0);
    }
  }
  __syncthreads();   // make wave-0's dinv_s visible to all waves

  // epilogue: Z[m][n] = dinv[m] * acc
  // C/D layout: n(col) = lane&15, m(row) = (lane>>4)*4 + reg
  float di[4];
#pragma unroll
  for (int r = 0; r < 4; r++) di[r] = dinv_s[16 * wv + qd * 4 + r];
#pragma unroll
  for (int nt = 0; nt < 4; nt++) {
#pragma unroll
    for (int r = 0; r < 4; r++) {
      int m = m0 + 16 * wv + qd * 4 + r;
      int n = n0 + nt * 16 + lm;
      Z[(size_t)m * C_ + n] = di[r] * acc[nt][r];
    }
  }
}

// ---------------------------------------------------------------------------
// out[i] = dinv[i] * (Z[i] + sum_{j in mask(i)} Z[j]) + bias
// One wave per node. Unchanged from the passing round-1 kernel (bit-exact
// summation order preserved; absmax sits at 2^-10, no numeric headroom).
// Kept as a separate dispatch: needs 8 blocks/CU occupancy for gather
// latency hiding, which the 2-blocks/CU cooperative grid can't provide.
__global__ __launch_bounds__(256) void aggregate(
    const uint32_t* __restrict__ mask, const float* __restrict__ Z,
    const float* __restrict__ bias, float* __restrict__ out) {
  __shared__ uint16_t lists[4][LIST_CAP];

  int blk   = blockIdx.x;            // 0..2047
  int batch = blk & 7;
  int group = blk >> 3;              // 0..255
  int wv    = threadIdx.x >> 6;      // wave 0..3 -> node within group
  int ln    = threadIdx.x & 63;
  int loc   = group * 4 + wv;        // local node 0..1023
  int node  = batch * N_ + loc;
  int c4    = ln * 4;

  // ---- build neighbor list in LDS (wave-synchronous) ----
  uint32_t bits = (ln < NW_) ? mask[(size_t)node * NW_ + ln] : 0u;
  int cnt = __popc(bits);
  int pfx = cnt;
#pragma unroll
  for (int off = 1; off < 64; off <<= 1) {
    int v = __shfl_up(pfx, off);
    if (ln >= off) pfx += v;
  }
  int total = __shfl(pfx, 63);       // degree (excluding self loop)
  pfx -= cnt;                        // exclusive prefix
  uint16_t* lst = lists[wv];
  int o = pfx, jb = ln * 32;
  while (bits) {
    int j = __ffs(bits) - 1;
    bits &= bits - 1;
    lst[o++] = (uint16_t)(jb + j);
  }
  if (ln == 0) {                     // pad to multiple of 4 (weight-0 below)
    int dd = total;
    while (dd & 3) lst[dd++] = 0;
  }
  // same-wave LDS write->read: lockstep wave64, program-order ds ops.

  const float* zb = Z + (size_t)batch * N_ * C_;
  float4 acc = *(const float4*)&zb[(size_t)loc * C_ + c4];   // self (eye) term

  for (int k = 0; k < total; k += 4) {
    ushort4 n4 = *(const ushort4*)&lst[k];
    float4 z0 = *(const float4*)&zb[(size_t)n4.x * C_ + c4];
    float4 z1 = *(const float4*)&zb[(size_t)n4.y * C_ + c4];
    float4 z2 = *(const float4*)&zb[(size_t)n4.z * C_ + c4];
    float4 z3 = *(const float4*)&zb[(size_t)n4.w * C_ + c4];
    float w1 = (k + 1 < total) ? 1.f : 0.f;
    float w2 = (k + 2 < total) ? 1.f : 0.f;
    float w3 = (k + 3 < total) ? 1.f : 0.f;
    acc.x += z0.x; acc.y += z0.y; acc.z += z0.z; acc.w += z0.w;
    acc.x += w1 * z1.x; acc.y += w1 * z1.y; acc.z += w1 * z1.z; acc.w += w1 * z1.w;
    acc.x += w2 * z2.x; acc.y += w2 * z2.y; acc.z += w2 * z2.z; acc.w += w2 * z2.w;
    acc.x += w3 * z3.x; acc.y += w3 * z3.y; acc.z += w3 * z3.z; acc.w += w3 * z3.w;
  }

  float di = rsqrtf((float)(total + 1));
  float4 bb = *(const float4*)&bias[c4];
  float4 o4;
  o4.x = di * acc.x + bb.x;
  o4.y = di * acc.y + bb.y;
  o4.z = di * acc.z + bb.z;
  o4.w = di * acc.w + bb.w;
  *(float4*)&out[(size_t)node * C_ + c4] = o4;
}

// ---------------------------------------------------------------------------
extern "C" void kernel_launch(void* const* d_in, const int* in_sizes, int n_in,
                              void* d_out, int out_size, void* d_ws,
                              size_t ws_size, hipStream_t stream) {
  const float* x    = (const float*)d_in[0];   // [B,N,C]
  const int*   ei   = (const int*)d_in[1];     // [2,E,B]
  const float* W    = (const float*)d_in[2];   // [C_OUT,C]
  const float* bias = (const float*)d_in[3];   // [C_OUT]
  float*       out  = (float*)d_out;           // [B,N,C_OUT]

  // workspace layout (byte offsets):
  //   mask @ 0x000000  1 MB   (BN_*NW_*4)
  //   Z    @ 0x100000  8 MB
  char* ws = (char*)d_ws;
  uint32_t* mask = (uint32_t*)(ws + 0x000000);
  float*    Z    = (float*)   (ws + 0x100000);

  // 2 dispatches total (was 5): fused {memset+scatter+gemm} cooperative
  // kernel, then aggregate.
  void* args[] = {(void*)&x, (void*)&ei, (void*)&W, (void*)&mask, (void*)&Z};
  hipLaunchCooperativeKernel((void*)fused_pre, dim3(512), dim3(256), args, 0,
                             stream);
  aggregate<<<BN_ / 4, 256, 0, stream>>>(mask, Z, bias, out);
}

// Round 3
// 95.182 us; speedup vs baseline: 3.2778x; 3.2778x over previous
//
#include <hip/hip_runtime.h>
#include <stdint.h>

// Problem constants (from reference)
#define B_   8
#define N_   1024
#define C_   256      // C == C_OUT == 256
#define E_   16384
#define BN_  (B_ * N_)        // 8192
#define NW_  (N_ / 32)        // 32 mask words per row
#define LIST_CAP 96           // per-wave LDS neighbor list; Poisson(16) tail ~0

typedef __attribute__((ext_vector_type(8))) short bf16x8;
typedef __attribute__((ext_vector_type(4))) float f32x4;

static __device__ __forceinline__ short f32_to_bf16(float f) {
  uint32_t u = __float_as_uint(f);
  uint32_t r = (u + 0x7fffu + ((u >> 16) & 1u)) >> 16;   // RNE
  return (short)r;
}
static __device__ __forceinline__ float bf16_to_f32(short s) {
  return __uint_as_float(((uint32_t)(uint16_t)s) << 16);
}

// ---------------------------------------------------------------------------
// 1) Scatter edges into per-(batch,src) dst-bitmask. atomicOr == .set(1.0)
//    dedup semantics (duplicate edges count once).
__global__ __launch_bounds__(256) void scatter_edges(
    const int* __restrict__ ei, uint32_t* __restrict__ mask) {
  int t = blockIdx.x * 256 + threadIdx.x;          // 0 .. E_*B_-1
  if (t >= E_ * B_) return;
  int b   = t & (B_ - 1);                          // layout [E, B]
  int src = ei[t];                                 // edge_index[0] flat
  int dst = ei[E_ * B_ + t];                       // edge_index[1] flat
  int row = b * N_ + src;
  atomicOr(&mask[row * NW_ + (dst >> 5)], 1u << (dst & 31));
}

// ---------------------------------------------------------------------------
// 2) Z = dinv[m] * (X @ W^T)[m]  via bf16x3 split MFMA (fp32-grade accuracy).
//    W-tile (64 x 256, hi/lo bf16) staged ONCE into LDS in the prologue;
//    A-fragments loaded DIRECTLY from global, so the K-loop has ZERO
//    barriers and the compiler software-pipelines it.
//    Tile swizzle: XCD x (= blockIdx&7 under hw round-robin) owns m-tiles
//    of batch x -> X re-reads are XCD-local L2 hits; Z slice (1 MB/XCD) is
//    what aggregate's batch=blk&7 swizzle reads back from the same XCD L2.
__global__ __launch_bounds__(256) void gemm_bf16x3(
    const float* __restrict__ X, const float* __restrict__ W,
    const uint32_t* __restrict__ mask, float* __restrict__ Z) {
  __shared__ __attribute__((aligned(16))) short Bh[32][64][8];  // 32 KB
  __shared__ __attribute__((aligned(16))) short Bl[32][64][8];  // 32 KB
  __shared__ int   dpart[4][64];
  __shared__ float dinv_s[64];

  int t   = threadIdx.x;
  int id  = blockIdx.x;            // 0..511
  int loc = id >> 3;               // 0..63  (per-XCD local id)
  int mt  = (id & 7) * 16 + (loc >> 2);   // m-tile 0..127; XCD x -> batch x
  int m0  = mt * 64;
  int n0  = (loc & 3) * 64;        // all 4 n-tiles of an m-panel on same XCD

  // ---- inline degree: popcount of mask rows m0..m0+63 ----
  {
    int row = t & 63, part = t >> 6;               // 4 threads per row
    const uint4* mp =
        (const uint4*)&mask[(size_t)(m0 + row) * NW_ + part * 8];
    uint4 a = mp[0], b = mp[1];
    dpart[part][row] = __popc(a.x) + __popc(a.y) + __popc(a.z) + __popc(a.w) +
                       __popc(b.x) + __popc(b.y) + __popc(b.z) + __popc(b.w);
  }

  // ---- stage whole W-tile (rows n0..n0+63, K=0..256) as hi/lo bf16 ----
#pragma unroll
  for (int i = 0; i < 8; i++) {
    int row = t & 63;
    int ch  = (t >> 6) * 8 + i;
    const float* wr = &W[(size_t)(n0 + row) * C_ + ch * 8];
    float w8[8];
    *(float4*)&w8[0] = *(const float4*)&wr[0];
    *(float4*)&w8[4] = *(const float4*)&wr[4];
    bf16x8 wh, wl;
#pragma unroll
    for (int j = 0; j < 8; j++) {
      short h = f32_to_bf16(w8[j]);
      wh[j] = h;
      wl[j] = f32_to_bf16(w8[j] - bf16_to_f32(h));
    }
    *(bf16x8*)&Bh[ch][row][0] = wh;
    *(bf16x8*)&Bl[ch][row][0] = wl;
  }
  __syncthreads();                 // covers dpart + Bh/Bl; only barrier pre-loop

  if (t < 64) {                    // wave 0 computes dinv while others compute
    int d = dpart[0][t] + dpart[1][t] + dpart[2][t] + dpart[3][t] + 1;
    dinv_s[t] = rsqrtf((float)d);
  }

  int wv = t >> 6;                 // wave 0..3 -> rows 16wv..16wv+15
  int ln = t & 63;
  int lm = ln & 15;                // frag row-in-tile
  int qd = ln >> 4;                // frag k-quad

  const float* xr = &X[(size_t)(m0 + 16 * wv + lm) * C_ + qd * 8];

  f32x4 acc[4];
#pragma unroll
  for (int i = 0; i < 4; i++) acc[i] = (f32x4){0.f, 0.f, 0.f, 0.f};

  // ---- barrier-free K loop: A from global, B from resident LDS ----
#pragma unroll
  for (int k0 = 0; k0 < C_; k0 += 32) {
    float xv[8];
    *(float4*)&xv[0] = *(const float4*)&xr[k0];
    *(float4*)&xv[4] = *(const float4*)&xr[k0 + 4];
    bf16x8 ah, al;
#pragma unroll
    for (int j = 0; j < 8; j++) {
      short h = f32_to_bf16(xv[j]);
      ah[j] = h;
      al[j] = f32_to_bf16(xv[j] - bf16_to_f32(h));
    }
    int cq = (k0 >> 3) + qd;
#pragma unroll
    for (int nt = 0; nt < 4; nt++) {
      bf16x8 bh = *(const bf16x8*)&Bh[cq][nt * 16 + lm][0];
      bf16x8 bl = *(const bf16x8*)&Bl[cq][nt * 16 + lm][0];
      acc[nt] = __builtin_amdgcn_mfma_f32_16x16x32_bf16(ah, bh, acc[nt], 0, 0, 0);
      acc[nt] = __builtin_amdgcn_mfma_f32_16x16x32_bf16(ah, bl, acc[nt], 0, 0, 0);
      acc[nt] = __builtin_amdgcn_mfma_f32_16x16x32_bf16(al, bh, acc[nt], 0, 0, 0);
    }
  }
  __syncthreads();   // make wave-0's dinv_s visible to all waves

  // ---- epilogue: Z[m][n] = dinv[m] * acc ----
  // C/D layout: n(col) = lane&15, m(row) = (lane>>4)*4 + reg
  float di[4];
#pragma unroll
  for (int r = 0; r < 4; r++) di[r] = dinv_s[16 * wv + qd * 4 + r];
#pragma unroll
  for (int nt = 0; nt < 4; nt++) {
#pragma unroll
    for (int r = 0; r < 4; r++) {
      int m = m0 + 16 * wv + qd * 4 + r;
      int n = n0 + nt * 16 + lm;
      Z[(size_t)m * C_ + n] = di[r] * acc[nt][r];
    }
  }
}

// ---------------------------------------------------------------------------
// 3) out[i] = dinv[i] * (Z[i] + sum_{j in mask(i)} Z[j]) + bias
//    One wave per node; shfl prefix-sum -> LDS neighbor list -> unroll-4
//    float4 gathers. batch = blockIdx & 7 keeps gathers XCD-local.
__global__ __launch_bounds__(256) void aggregate(
    const uint32_t* __restrict__ mask, const float* __restrict__ Z,
    const float* __restrict__ bias, float* __restrict__ out) {
  __shared__ uint16_t lists[4][LIST_CAP];

  int blk   = blockIdx.x;            // 0..2047
  int batch = blk & 7;
  int group = blk >> 3;              // 0..255
  int wv    = threadIdx.x >> 6;      // wave 0..3 -> node within group
  int ln    = threadIdx.x & 63;
  int loc   = group * 4 + wv;        // local node 0..1023
  int node  = batch * N_ + loc;
  int c4    = ln * 4;

  uint32_t bits = (ln < NW_) ? mask[(size_t)node * NW_ + ln] : 0u;
  int cnt = __popc(bits);
  int pfx = cnt;
#pragma unroll
  for (int off = 1; off < 64; off <<= 1) {
    int v = __shfl_up(pfx, off);
    if (ln >= off) pfx += v;
  }
  int total = __shfl(pfx, 63);       // degree (excluding self loop)
  pfx -= cnt;                        // exclusive prefix
  uint16_t* lst = lists[wv];
  int o = pfx, jb = ln * 32;
  while (bits) {
    int j = __ffs(bits) - 1;
    bits &= bits - 1;
    lst[o++] = (uint16_t)(jb + j);
  }
  if (ln == 0) {                     // pad to multiple of 4 (weight-0 below)
    int dd = total;
    while (dd & 3) lst[dd++] = 0;
  }
  // same-wave LDS write->read: lockstep wave64, program-order ds ops.

  const float* zb = Z + (size_t)batch * N_ * C_;
  float4 acc = *(const float4*)&zb[(size_t)loc * C_ + c4];   // self (eye) term

  for (int k = 0; k < total; k += 4) {
    ushort4 n4 = *(const ushort4*)&lst[k];
    float4 z0 = *(const float4*)&zb[(size_t)n4.x * C_ + c4];
    float4 z1 = *(const float4*)&zb[(size_t)n4.y * C_ + c4];
    float4 z2 = *(const float4*)&zb[(size_t)n4.z * C_ + c4];
    float4 z3 = *(const float4*)&zb[(size_t)n4.w * C_ + c4];
    float w1 = (k + 1 < total) ? 1.f : 0.f;
    float w2 = (k + 2 < total) ? 1.f : 0.f;
    float w3 = (k + 3 < total) ? 1.f : 0.f;
    acc.x += z0.x; acc.y += z0.y; acc.z += z0.z; acc.w += z0.w;
    acc.x += w1 * z1.x; acc.y += w1 * z1.y; acc.z += w1 * z1.z; acc.w += w1 * z1.w;
    acc.x += w2 * z2.x; acc.y += w2 * z2.y; acc.z += w2 * z2.z; acc.w += w2 * z2.w;
    acc.x += w3 * z3.x; acc.y += w3 * z3.y; acc.z += w3 * z3.z; acc.w += w3 * z3.w;
  }

  float di = rsqrtf((float)(total + 1));
  float4 bb = *(const float4*)&bias[c4];
  float4 o4;
  o4.x = di * acc.x + bb.x;
  o4.y = di * acc.y + bb.y;
  o4.z = di * acc.z + bb.z;
  o4.w = di * acc.w + bb.w;
  *(float4*)&out[(size_t)node * C_ + c4] = o4;
}

// ---------------------------------------------------------------------------
extern "C" void kernel_launch(void* const* d_in, const int* in_sizes, int n_in,
                              void* d_out, int out_size, void* d_ws,
                              size_t ws_size, hipStream_t stream) {
  const float* x    = (const float*)d_in[0];   // [B,N,C]
  const int*   ei   = (const int*)d_in[1];     // [2,E,B]
  const float* W    = (const float*)d_in[2];   // [C_OUT,C]
  const float* bias = (const float*)d_in[3];   // [C_OUT]
  float*       out  = (float*)d_out;           // [B,N,C_OUT]

  // workspace layout (byte offsets):
  //   mask @ 0x000000  1 MB   (BN_*NW_*4)
  //   Z    @ 0x100000  8 MB
  char* ws = (char*)d_ws;
  uint32_t* mask = (uint32_t*)(ws + 0x000000);
  float*    Z    = (float*)   (ws + 0x100000);

  hipMemsetAsync(mask, 0, (size_t)BN_ * NW_ * 4, stream);

  scatter_edges<<<(E_ * B_) / 256, 256, 0, stream>>>(ei, mask);
  gemm_bf16x3<<<512, 256, 0, stream>>>(x, W, mask, Z);
  aggregate<<<BN_ / 4, 256, 0, stream>>>(mask, Z, bias, out);
}